// Round 1
// baseline (4449.292 us; speedup 1.0000x reference)
//
#include <hip/hip_runtime.h>

#define N_NODES 32768
#define N_EDGES 262144
#define NB 8
#define TW 25
#define H 128

__device__ __forceinline__ float swishf(float x) {
    return x / (1.0f + __expf(-x));
}

// ---------------------------------------------------------------------------
// init: posx/post
__global__ void init_kernel(const float* __restrict__ pos,
                            float* __restrict__ posx, float* __restrict__ post) {
    int i = blockIdx.x * 256 + threadIdx.x;
    if (i < N_NODES) {
        post[i] = pos[i * 2 + 0] * 0.25f;    // /TMAX
        posx[i] = pos[i * 2 + 1] * 0.0625f;  // /16
    }
}

// edge target counts
__global__ void cnt_kernel(const int* __restrict__ tgt, float* __restrict__ cnt) {
    int i = blockIdx.x * 256 + threadIdx.x;
    if (i < N_EDGES) atomicAdd(&cnt[tgt[i]], 1.0f);
}

// ---------------------------------------------------------------------------
// Encoder: h = swish(swish(ni @ We1 + be1) @ We2 + be2), ni = [u(25), posx, post]
__global__ __launch_bounds__(256) void encoder_kernel(
    const float* __restrict__ u, const float* __restrict__ posx,
    const float* __restrict__ post,
    const float* __restrict__ We1, const float* __restrict__ be1,
    const float* __restrict__ We2, const float* __restrict__ be2,
    float* __restrict__ h)
{
    __shared__ __align__(16) float As[64 * 36];
    __shared__ __align__(16) float Ws[32 * 128];
    __shared__ __align__(16) float Ms[64 * 128];

    int t = threadIdx.x;
    int n0 = blockIdx.x * 64;
    int rg = t >> 5, cg = t & 31;

    float acc[8][4] = {};
    // GEMM1: K=27, single chunk of 32 (zero-padded)
    {
        int kk = t >> 3, cb = (t & 7) * 16;
        #pragma unroll
        for (int j = 0; j < 4; ++j) {
            float4 w = make_float4(0.f, 0.f, 0.f, 0.f);
            if (kk < 27) w = *(const float4*)&We1[kk * 128 + cb + j * 4];
            *(float4*)&Ws[kk * 128 + cb + j * 4] = w;
        }
        int el = t >> 2, kb = (t & 3) * 8, n = n0 + el;
        float v[8];
        #pragma unroll
        for (int j = 0; j < 8; ++j) {
            int k = kb + j;
            float x = 0.f;
            if (k < 25) x = u[n * 25 + k];
            else if (k == 25) x = posx[n];
            else if (k == 26) x = post[n];
            v[j] = x;
        }
        #pragma unroll
        for (int j = 0; j < 8; j += 4)
            *(float4*)&As[el * 36 + kb + j] = make_float4(v[j], v[j+1], v[j+2], v[j+3]);
        __syncthreads();
        #pragma unroll 4
        for (int kk2 = 0; kk2 < 32; ++kk2) {
            float4 b = *(const float4*)&Ws[kk2 * 128 + cg * 4];
            float a[8];
            #pragma unroll
            for (int i = 0; i < 8; ++i) a[i] = As[(rg * 8 + i) * 36 + kk2];
            #pragma unroll
            for (int i = 0; i < 8; ++i) {
                acc[i][0] += a[i] * b.x; acc[i][1] += a[i] * b.y;
                acc[i][2] += a[i] * b.z; acc[i][3] += a[i] * b.w;
            }
        }
        __syncthreads();
    }
    // swish + bias -> Ms
    {
        float4 b1 = *(const float4*)&be1[cg * 4];
        #pragma unroll
        for (int i = 0; i < 8; ++i) {
            float4 m;
            m.x = swishf(acc[i][0] + b1.x);
            m.y = swishf(acc[i][1] + b1.y);
            m.z = swishf(acc[i][2] + b1.z);
            m.w = swishf(acc[i][3] + b1.w);
            *(float4*)&Ms[(rg * 8 + i) * 128 + cg * 4] = m;
        }
        __syncthreads();
    }
    // GEMM2: K=128
    float acc2[8][4] = {};
    for (int k0 = 0; k0 < 128; k0 += 32) {
        int kk = t >> 3, cb = (t & 7) * 16;
        #pragma unroll
        for (int j = 0; j < 4; ++j)
            *(float4*)&Ws[kk * 128 + cb + j * 4] =
                *(const float4*)&We2[(k0 + kk) * 128 + cb + j * 4];
        __syncthreads();
        #pragma unroll 4
        for (int kk2 = 0; kk2 < 32; ++kk2) {
            float4 b = *(const float4*)&Ws[kk2 * 128 + cg * 4];
            float a[8];
            #pragma unroll
            for (int i = 0; i < 8; ++i) a[i] = Ms[(rg * 8 + i) * 128 + (k0 + kk2)];
            #pragma unroll
            for (int i = 0; i < 8; ++i) {
                acc2[i][0] += a[i] * b.x; acc2[i][1] += a[i] * b.y;
                acc2[i][2] += a[i] * b.z; acc2[i][3] += a[i] * b.w;
            }
        }
        __syncthreads();
    }
    {
        float4 b2 = *(const float4*)&be2[cg * 4];
        #pragma unroll
        for (int i = 0; i < 8; ++i) {
            int n = n0 + rg * 8 + i;
            float4 o;
            o.x = swishf(acc2[i][0] + b2.x);
            o.y = swishf(acc2[i][1] + b2.y);
            o.z = swishf(acc2[i][2] + b2.z);
            o.w = swishf(acc2[i][3] + b2.w);
            *(float4*)&h[n * 128 + cg * 4] = o;
        }
    }
}

// ---------------------------------------------------------------------------
// Message MLP + scatter-add into agg.
// m_in(283) = [h[tgt](128), h[src](128), u[tgt]-u[src](25), posx_d(1), post[tgt](1)]
__global__ __launch_bounds__(256) void message_kernel(
    const float* __restrict__ h, const float* __restrict__ u,
    const float* __restrict__ posx, const float* __restrict__ post,
    const int* __restrict__ src, const int* __restrict__ tgt,
    const float* __restrict__ Wm1, const float* __restrict__ bm1,
    const float* __restrict__ Wm2, const float* __restrict__ bm2,
    float* __restrict__ agg)
{
    __shared__ __align__(16) float As[64 * 36];
    __shared__ __align__(16) float Ws[32 * 128];
    __shared__ __align__(16) float Ms[64 * 128];
    __shared__ int srcS[64];
    __shared__ int tgtS[64];

    int t = threadIdx.x;
    int e0 = blockIdx.x * 64;
    if (t < 64) { srcS[t] = src[e0 + t]; tgtS[t] = tgt[e0 + t]; }
    __syncthreads();

    int rg = t >> 5, cg = t & 31;
    float acc[8][4] = {};

    // GEMM1: K=283 in 9 chunks of 32
    for (int k0 = 0; k0 < 288; k0 += 32) {
        int kk = t >> 3, cb = (t & 7) * 16, kg = k0 + kk;
        #pragma unroll
        for (int j = 0; j < 4; ++j) {
            float4 w = make_float4(0.f, 0.f, 0.f, 0.f);
            if (kg < 283) w = *(const float4*)&Wm1[kg * 128 + cb + j * 4];
            *(float4*)&Ws[kk * 128 + cb + j * 4] = w;
        }
        int el = t >> 2, kb = (t & 3) * 8;
        int s = srcS[el], g = tgtS[el];
        float v[8];
        #pragma unroll
        for (int j = 0; j < 8; ++j) {
            int k = k0 + kb + j;
            float x = 0.f;
            if (k < 128) x = h[g * 128 + k];
            else if (k < 256) x = h[s * 128 + (k - 128)];
            else if (k < 281) x = u[g * 25 + (k - 256)] - u[s * 25 + (k - 256)];
            else if (k == 281) x = posx[g] - posx[s];
            else if (k == 282) x = post[g];
            v[j] = x;
        }
        #pragma unroll
        for (int j = 0; j < 8; j += 4)
            *(float4*)&As[el * 36 + kb + j] = make_float4(v[j], v[j+1], v[j+2], v[j+3]);
        __syncthreads();
        #pragma unroll 4
        for (int kk2 = 0; kk2 < 32; ++kk2) {
            float4 b = *(const float4*)&Ws[kk2 * 128 + cg * 4];
            float a[8];
            #pragma unroll
            for (int i = 0; i < 8; ++i) a[i] = As[(rg * 8 + i) * 36 + kk2];
            #pragma unroll
            for (int i = 0; i < 8; ++i) {
                acc[i][0] += a[i] * b.x; acc[i][1] += a[i] * b.y;
                acc[i][2] += a[i] * b.z; acc[i][3] += a[i] * b.w;
            }
        }
        __syncthreads();
    }
    // swish -> Ms
    {
        float4 b1 = *(const float4*)&bm1[cg * 4];
        #pragma unroll
        for (int i = 0; i < 8; ++i) {
            float4 m;
            m.x = swishf(acc[i][0] + b1.x);
            m.y = swishf(acc[i][1] + b1.y);
            m.z = swishf(acc[i][2] + b1.z);
            m.w = swishf(acc[i][3] + b1.w);
            *(float4*)&Ms[(rg * 8 + i) * 128 + cg * 4] = m;
        }
        __syncthreads();
    }
    // GEMM2: K=128
    float acc2[8][4] = {};
    for (int k0 = 0; k0 < 128; k0 += 32) {
        int kk = t >> 3, cb = (t & 7) * 16;
        #pragma unroll
        for (int j = 0; j < 4; ++j)
            *(float4*)&Ws[kk * 128 + cb + j * 4] =
                *(const float4*)&Wm2[(k0 + kk) * 128 + cb + j * 4];
        __syncthreads();
        #pragma unroll 4
        for (int kk2 = 0; kk2 < 32; ++kk2) {
            float4 b = *(const float4*)&Ws[kk2 * 128 + cg * 4];
            float a[8];
            #pragma unroll
            for (int i = 0; i < 8; ++i) a[i] = Ms[(rg * 8 + i) * 128 + (k0 + kk2)];
            #pragma unroll
            for (int i = 0; i < 8; ++i) {
                acc2[i][0] += a[i] * b.x; acc2[i][1] += a[i] * b.y;
                acc2[i][2] += a[i] * b.z; acc2[i][3] += a[i] * b.w;
            }
        }
        __syncthreads();
    }
    // swish + atomic scatter-add
    {
        float4 b2 = *(const float4*)&bm2[cg * 4];
        #pragma unroll
        for (int i = 0; i < 8; ++i) {
            int g = tgtS[rg * 8 + i];
            float* dst = &agg[g * 128 + cg * 4];
            atomicAdd(dst + 0, swishf(acc2[i][0] + b2.x));
            atomicAdd(dst + 1, swishf(acc2[i][1] + b2.y));
            atomicAdd(dst + 2, swishf(acc2[i][2] + b2.z));
            atomicAdd(dst + 3, swishf(acc2[i][3] + b2.w));
        }
    }
}

// ---------------------------------------------------------------------------
// Update MLP: h += swish(swish([h, agg/cnt, post] @ Wu1 + bu1) @ Wu2 + bu2)
__global__ __launch_bounds__(256) void update_kernel(
    float* __restrict__ h, const float* __restrict__ agg,
    const float* __restrict__ cnt, const float* __restrict__ post,
    const float* __restrict__ Wu1, const float* __restrict__ bu1,
    const float* __restrict__ Wu2, const float* __restrict__ bu2)
{
    __shared__ __align__(16) float As[64 * 36];
    __shared__ __align__(16) float Ws[32 * 128];
    __shared__ __align__(16) float Ms[64 * 128];
    __shared__ float icS[64];

    int t = threadIdx.x;
    int n0 = blockIdx.x * 64;
    if (t < 64) icS[t] = 1.0f / fmaxf(cnt[n0 + t], 1.0f);
    __syncthreads();

    int rg = t >> 5, cg = t & 31;
    float acc[8][4] = {};

    // GEMM1: K=257 in 9 chunks of 32
    for (int k0 = 0; k0 < 288; k0 += 32) {
        int kk = t >> 3, cb = (t & 7) * 16, kg = k0 + kk;
        #pragma unroll
        for (int j = 0; j < 4; ++j) {
            float4 w = make_float4(0.f, 0.f, 0.f, 0.f);
            if (kg < 257) w = *(const float4*)&Wu1[kg * 128 + cb + j * 4];
            *(float4*)&Ws[kk * 128 + cb + j * 4] = w;
        }
        int el = t >> 2, kb = (t & 3) * 8, n = n0 + el;
        float v[8];
        #pragma unroll
        for (int j = 0; j < 8; ++j) {
            int k = k0 + kb + j;
            float x = 0.f;
            if (k < 128) x = h[n * 128 + k];
            else if (k < 256) x = agg[n * 128 + (k - 128)] * icS[el];
            else if (k == 256) x = post[n];
            v[j] = x;
        }
        #pragma unroll
        for (int j = 0; j < 8; j += 4)
            *(float4*)&As[el * 36 + kb + j] = make_float4(v[j], v[j+1], v[j+2], v[j+3]);
        __syncthreads();
        #pragma unroll 4
        for (int kk2 = 0; kk2 < 32; ++kk2) {
            float4 b = *(const float4*)&Ws[kk2 * 128 + cg * 4];
            float a[8];
            #pragma unroll
            for (int i = 0; i < 8; ++i) a[i] = As[(rg * 8 + i) * 36 + kk2];
            #pragma unroll
            for (int i = 0; i < 8; ++i) {
                acc[i][0] += a[i] * b.x; acc[i][1] += a[i] * b.y;
                acc[i][2] += a[i] * b.z; acc[i][3] += a[i] * b.w;
            }
        }
        __syncthreads();
    }
    {
        float4 b1 = *(const float4*)&bu1[cg * 4];
        #pragma unroll
        for (int i = 0; i < 8; ++i) {
            float4 m;
            m.x = swishf(acc[i][0] + b1.x);
            m.y = swishf(acc[i][1] + b1.y);
            m.z = swishf(acc[i][2] + b1.z);
            m.w = swishf(acc[i][3] + b1.w);
            *(float4*)&Ms[(rg * 8 + i) * 128 + cg * 4] = m;
        }
        __syncthreads();
    }
    float acc2[8][4] = {};
    for (int k0 = 0; k0 < 128; k0 += 32) {
        int kk = t >> 3, cb = (t & 7) * 16;
        #pragma unroll
        for (int j = 0; j < 4; ++j)
            *(float4*)&Ws[kk * 128 + cb + j * 4] =
                *(const float4*)&Wu2[(k0 + kk) * 128 + cb + j * 4];
        __syncthreads();
        #pragma unroll 4
        for (int kk2 = 0; kk2 < 32; ++kk2) {
            float4 b = *(const float4*)&Ws[kk2 * 128 + cg * 4];
            float a[8];
            #pragma unroll
            for (int i = 0; i < 8; ++i) a[i] = Ms[(rg * 8 + i) * 128 + (k0 + kk2)];
            #pragma unroll
            for (int i = 0; i < 8; ++i) {
                acc2[i][0] += a[i] * b.x; acc2[i][1] += a[i] * b.y;
                acc2[i][2] += a[i] * b.z; acc2[i][3] += a[i] * b.w;
            }
        }
        __syncthreads();
    }
    {
        float4 b2 = *(const float4*)&bu2[cg * 4];
        #pragma unroll
        for (int i = 0; i < 8; ++i) {
            int n = n0 + rg * 8 + i;
            float4 old = *(float4*)&h[n * 128 + cg * 4];
            old.x += swishf(acc2[i][0] + b2.x);
            old.y += swishf(acc2[i][1] + b2.y);
            old.z += swishf(acc2[i][2] + b2.z);
            old.w += swishf(acc2[i][3] + b2.w);
            *(float4*)&h[n * 128 + cg * 4] = old;
        }
    }
}

// ---------------------------------------------------------------------------
// batch stats: per (batch, channel) sum and sumsq. 128 threads, 64 nodes/block.
__global__ __launch_bounds__(128) void stats_kernel(const float* __restrict__ h,
                                                    float* __restrict__ stats) {
    int c = threadIdx.x;
    int n0 = blockIdx.x * 64;
    int b = n0 >> 12;  // 4096 nodes per batch
    float s = 0.f, s2 = 0.f;
    for (int i = 0; i < 64; ++i) {
        float v = h[(n0 + i) * 128 + c];
        s += v; s2 += v * v;
    }
    atomicAdd(&stats[b * 128 + c], s);
    atomicAdd(&stats[(NB + b) * 128 + c], s2);
}

__global__ __launch_bounds__(256) void norm_kernel(float* __restrict__ h,
                                                   const float* __restrict__ stats) {
    int idx = blockIdx.x * 256 + threadIdx.x;
    int n = idx >> 7, c = idx & 127;
    int b = n >> 12;
    float mean = stats[b * 128 + c] * (1.f / 4096.f);
    float var = stats[(NB + b) * 128 + c] * (1.f / 4096.f) - mean * mean;
    float v = h[idx];
    h[idx] = (v - mean) * rsqrtf(var + 1e-5f);
}

// ---------------------------------------------------------------------------
// Conv head: one wave per node.
__global__ __launch_bounds__(64) void conv_kernel(
    const float* __restrict__ h, const float* __restrict__ u,
    const float* __restrict__ Wc1, const float* __restrict__ bc1,
    const float* __restrict__ Wc2, const float* __restrict__ bc2,
    float* __restrict__ out)
{
    __shared__ float hs[128];
    __shared__ float c1[8 * 38];
    int n = blockIdx.x;
    int t = threadIdx.x;
    hs[t] = h[n * 128 + t];
    hs[t + 64] = h[n * 128 + t + 64];
    __syncthreads();
    for (int idx = t; idx < 304; idx += 64) {
        int o = idx / 38, p = idx % 38;
        float s = bc1[o];
        #pragma unroll
        for (int k = 0; k < 16; ++k) s += hs[p * 3 + k] * Wc1[o * 16 + k];
        c1[o * 38 + p] = swishf(s);
    }
    __syncthreads();
    if (t < TW) {
        float s = bc2[0];
        #pragma unroll
        for (int o = 0; o < 8; ++o)
            for (int k = 0; k < 14; ++k)
                s += c1[o * 38 + t + k] * Wc2[o * 14 + k];
        float dt_cum = (float)(t + 1) * (4.0f / 250.0f);
        out[n * TW + t] = u[n * 25 + 24] + dt_cum * s;
    }
}

// ---------------------------------------------------------------------------
extern "C" void kernel_launch(void* const* d_in, const int* in_sizes, int n_in,
                              void* d_out, int out_size, void* d_ws, size_t ws_size,
                              hipStream_t stream)
{
    const float* u    = (const float*)d_in[0];
    const float* pos  = (const float*)d_in[1];
    const int*   ei   = (const int*)d_in[2];
    const float* We1  = (const float*)d_in[4];
    const float* be1  = (const float*)d_in[5];
    const float* We2  = (const float*)d_in[6];
    const float* be2  = (const float*)d_in[7];
    const float* Wm1  = (const float*)d_in[8];
    const float* bm1  = (const float*)d_in[9];
    const float* Wm2  = (const float*)d_in[10];
    const float* bm2  = (const float*)d_in[11];
    const float* Wu1  = (const float*)d_in[12];
    const float* bu1  = (const float*)d_in[13];
    const float* Wu2  = (const float*)d_in[14];
    const float* bu2  = (const float*)d_in[15];
    const float* Wc1  = (const float*)d_in[16];
    const float* bc1  = (const float*)d_in[17];
    const float* Wc2  = (const float*)d_in[18];
    const float* bc2  = (const float*)d_in[19];
    float* out = (float*)d_out;

    char* ws = (char*)d_ws;
    float* h     = (float*)(ws);                      // N*128
    float* agg   = (float*)(ws + 16777216);           // N*128
    float* cnt   = (float*)(ws + 33554432);           // N
    float* posx  = (float*)(ws + 33685504);           // N
    float* post  = (float*)(ws + 33816576);           // N
    float* stats = (float*)(ws + 33947648);           // 2*8*128

    const int* srcp = ei;
    const int* tgtp = ei + N_EDGES;

    init_kernel<<<N_NODES / 256, 256, 0, stream>>>(pos, posx, post);
    hipMemsetAsync(cnt, 0, N_NODES * sizeof(float), stream);
    cnt_kernel<<<N_EDGES / 256, 256, 0, stream>>>(tgtp, cnt);
    encoder_kernel<<<N_NODES / 64, 256, 0, stream>>>(u, posx, post, We1, be1, We2, be2, h);

    for (int l = 0; l < 6; ++l) {
        hipMemsetAsync(agg, 0, N_NODES * 128 * sizeof(float), stream);
        message_kernel<<<N_EDGES / 64, 256, 0, stream>>>(
            h, u, posx, post, srcp, tgtp,
            Wm1 + (size_t)l * 283 * 128, bm1 + l * 128,
            Wm2 + (size_t)l * 128 * 128, bm2 + l * 128, agg);
        update_kernel<<<N_NODES / 64, 256, 0, stream>>>(
            h, agg, cnt, post,
            Wu1 + (size_t)l * 257 * 128, bu1 + l * 128,
            Wu2 + (size_t)l * 128 * 128, bu2 + l * 128);
        hipMemsetAsync(stats, 0, 2 * NB * 128 * sizeof(float), stream);
        stats_kernel<<<N_NODES / 64, 128, 0, stream>>>(h, stats);
        norm_kernel<<<N_NODES * 128 / 256, 256, 0, stream>>>(h, stats);
    }

    conv_kernel<<<N_NODES, 64, 0, stream>>>(h, u, Wc1, bc1, Wc2, bc2, out);
}

// Round 2
// 1065.665 us; speedup vs baseline: 4.1751x; 4.1751x over previous
//
#include <hip/hip_runtime.h>
#include <stdint.h>

#define N_NODES 32768
#define N_EDGES 262144
#define NB 8
#define TW 25

typedef __attribute__((ext_vector_type(8))) short short8;
typedef __attribute__((ext_vector_type(4))) float floatx4;

__device__ __forceinline__ float swishf(float x) { return x / (1.0f + __expf(-x)); }

__device__ __forceinline__ unsigned short f2bf(float x) {
    union { float f; unsigned u; } v; v.f = x;
    unsigned r = v.u + 0x7FFFu + ((v.u >> 16) & 1u);
    return (unsigned short)(r >> 16);
}
__device__ __forceinline__ float bf2f(unsigned short b) {
    union { unsigned u; float f; } v; v.u = ((unsigned)b) << 16; return v.f;
}

// ---------------------------------------------------------------------------
__global__ void init_kernel(const float* __restrict__ pos,
                            float* __restrict__ posx, float* __restrict__ post) {
    int i = blockIdx.x * 256 + threadIdx.x;
    if (i < N_NODES) {
        post[i] = pos[i * 2 + 0] * 0.25f;
        posx[i] = pos[i * 2 + 1] * 0.0625f;
    }
}

__global__ void deg_kernel(const int* __restrict__ tgt, int* __restrict__ deg) {
    int i = blockIdx.x * 256 + threadIdx.x;
    if (i < N_EDGES) atomicAdd(&deg[tgt[i]], 1);
}

// exclusive scan of deg -> rowptr (+cursor copy), single block
__global__ __launch_bounds__(1024) void scan_kernel(const int* __restrict__ deg,
                                                    int* __restrict__ rowptr,
                                                    int* __restrict__ cursor) {
    __shared__ int ps[1024];
    int t = threadIdx.x;
    int base = t * 32;
    int tot = 0;
    for (int i = 0; i < 32; ++i) tot += deg[base + i];
    ps[t] = tot;
    __syncthreads();
    for (int off = 1; off < 1024; off <<= 1) {
        int v = (t >= off) ? ps[t - off] : 0;
        __syncthreads();
        ps[t] += v;
        __syncthreads();
    }
    int run = ps[t] - tot;  // exclusive
    for (int i = 0; i < 32; ++i) {
        rowptr[base + i] = run;
        cursor[base + i] = run;
        run += deg[base + i];
    }
    if (t == 1023) rowptr[N_NODES] = run;
}

__global__ void scatter_kernel(const int* __restrict__ tgt, int* __restrict__ cursor,
                               int* __restrict__ perm) {
    int i = blockIdx.x * 256 + threadIdx.x;
    if (i < N_EDGES) {
        int p = atomicAdd(&cursor[tgt[i]], 1);
        perm[p] = i;
    }
}

// ---------------------------------------------------------------------------
// Pack weight W (layers x Kreal x 128) into MFMA B-fragment order, bf16,
// zero-padded to Kc*32 in K. Frag id = ((l*Kc + c)*8 + t8)*64 + lane; each
// holds 8 bf16: B[k = c*32 + (lane>>4)*8 + j][n = t8*16 + (lane&15)].
__global__ __launch_bounds__(256) void pack_kernel(const float* __restrict__ W,
                                                   unsigned short* __restrict__ Wp,
                                                   int Kreal, int Kc, int total) {
    int id = blockIdx.x * 256 + threadIdx.x;
    if (id >= total) return;
    int lane = id & 63;
    int t8 = (id >> 6) & 7;
    int rest = id >> 9;
    int c = rest % Kc;
    int l = rest / Kc;
    int n = t8 * 16 + (lane & 15);
    int kb = c * 32 + (lane >> 4) * 8;
    short8 v;
    #pragma unroll
    for (int j = 0; j < 8; ++j) {
        int k = kb + j;
        float x = (k < Kreal) ? W[((size_t)l * Kreal + k) * 128 + n] : 0.f;
        v[j] = (short)f2bf(x);
    }
    *(short8*)(Wp + (size_t)id * 8) = v;
}

// ---------------------------------------------------------------------------
// Encoder (fp32 VALU, small): h = swish(swish(ni@We1+be1)@We2+be2); writes h + h_bf
__global__ __launch_bounds__(256) void encoder_kernel(
    const float* __restrict__ u, const float* __restrict__ posx,
    const float* __restrict__ post,
    const float* __restrict__ We1, const float* __restrict__ be1,
    const float* __restrict__ We2, const float* __restrict__ be2,
    float* __restrict__ h, unsigned short* __restrict__ h_bf)
{
    __shared__ __align__(16) float As[64 * 36];
    __shared__ __align__(16) float Ws[32 * 128];
    __shared__ __align__(16) float Ms[64 * 128];

    int t = threadIdx.x;
    int n0 = blockIdx.x * 64;
    int rg = t >> 5, cg = t & 31;

    float acc[8][4] = {};
    {
        int kk = t >> 3, cb = (t & 7) * 16;
        #pragma unroll
        for (int j = 0; j < 4; ++j) {
            float4 w = make_float4(0.f, 0.f, 0.f, 0.f);
            if (kk < 27) w = *(const float4*)&We1[kk * 128 + cb + j * 4];
            *(float4*)&Ws[kk * 128 + cb + j * 4] = w;
        }
        int el = t >> 2, kb = (t & 3) * 8, n = n0 + el;
        float v[8];
        #pragma unroll
        for (int j = 0; j < 8; ++j) {
            int k = kb + j;
            float x = 0.f;
            if (k < 25) x = u[n * 25 + k];
            else if (k == 25) x = posx[n];
            else if (k == 26) x = post[n];
            v[j] = x;
        }
        #pragma unroll
        for (int j = 0; j < 8; j += 4)
            *(float4*)&As[el * 36 + kb + j] = make_float4(v[j], v[j+1], v[j+2], v[j+3]);
        __syncthreads();
        #pragma unroll 4
        for (int kk2 = 0; kk2 < 32; ++kk2) {
            float4 b = *(const float4*)&Ws[kk2 * 128 + cg * 4];
            float a[8];
            #pragma unroll
            for (int i = 0; i < 8; ++i) a[i] = As[(rg * 8 + i) * 36 + kk2];
            #pragma unroll
            for (int i = 0; i < 8; ++i) {
                acc[i][0] += a[i] * b.x; acc[i][1] += a[i] * b.y;
                acc[i][2] += a[i] * b.z; acc[i][3] += a[i] * b.w;
            }
        }
        __syncthreads();
    }
    {
        float4 b1 = *(const float4*)&be1[cg * 4];
        #pragma unroll
        for (int i = 0; i < 8; ++i) {
            float4 m;
            m.x = swishf(acc[i][0] + b1.x);
            m.y = swishf(acc[i][1] + b1.y);
            m.z = swishf(acc[i][2] + b1.z);
            m.w = swishf(acc[i][3] + b1.w);
            *(float4*)&Ms[(rg * 8 + i) * 128 + cg * 4] = m;
        }
        __syncthreads();
    }
    float acc2[8][4] = {};
    for (int k0 = 0; k0 < 128; k0 += 32) {
        int kk = t >> 3, cb = (t & 7) * 16;
        #pragma unroll
        for (int j = 0; j < 4; ++j)
            *(float4*)&Ws[kk * 128 + cb + j * 4] =
                *(const float4*)&We2[(k0 + kk) * 128 + cb + j * 4];
        __syncthreads();
        #pragma unroll 4
        for (int kk2 = 0; kk2 < 32; ++kk2) {
            float4 b = *(const float4*)&Ws[kk2 * 128 + cg * 4];
            float a[8];
            #pragma unroll
            for (int i = 0; i < 8; ++i) a[i] = Ms[(rg * 8 + i) * 128 + (k0 + kk2)];
            #pragma unroll
            for (int i = 0; i < 8; ++i) {
                acc2[i][0] += a[i] * b.x; acc2[i][1] += a[i] * b.y;
                acc2[i][2] += a[i] * b.z; acc2[i][3] += a[i] * b.w;
            }
        }
        __syncthreads();
    }
    {
        float4 b2 = *(const float4*)&be2[cg * 4];
        #pragma unroll
        for (int i = 0; i < 8; ++i) {
            int n = n0 + rg * 8 + i;
            float4 o;
            o.x = swishf(acc2[i][0] + b2.x);
            o.y = swishf(acc2[i][1] + b2.y);
            o.z = swishf(acc2[i][2] + b2.z);
            o.w = swishf(acc2[i][3] + b2.w);
            *(float4*)&h[(size_t)n * 128 + cg * 4] = o;
            unsigned short* hb = h_bf + (size_t)n * 128 + cg * 4;
            uint2 pk;
            pk.x = (unsigned)f2bf(o.x) | ((unsigned)f2bf(o.y) << 16);
            pk.y = (unsigned)f2bf(o.z) | ((unsigned)f2bf(o.w) << 16);
            *(uint2*)hb = pk;
        }
    }
}

// ---------------------------------------------------------------------------
// MFMA message MLP. Block = 64 edges, 4 waves; wave w owns rows 16w..16w+16.
// CSR=1: edges taken in tgt-sorted order (perm), msg rows written to sorted
// slots (coalesced). CSR=0: fp32 atomic scatter into agg.
template<int CSR>
__global__ __launch_bounds__(256) void message_kernel(
    const unsigned short* __restrict__ h_bf, const float* __restrict__ u,
    const float* __restrict__ posx, const float* __restrict__ post,
    const int* __restrict__ src, const int* __restrict__ tgt,
    const int* __restrict__ perm,
    const unsigned short* __restrict__ W1p, const float* __restrict__ b1,
    const unsigned short* __restrict__ W2p, const float* __restrict__ b2,
    unsigned short* __restrict__ msg, float* __restrict__ agg)
{
    __shared__ unsigned short Ms[64 * 136];  // stride 136 bf16 = 272B (16B-aligned rows, conflict-padded)
    __shared__ int srcS[64], tgtS[64];
    int t = threadIdx.x;
    int e0 = blockIdx.x * 64;
    if (t < 64) {
        int e = CSR ? perm[e0 + t] : (e0 + t);
        srcS[t] = src[e]; tgtS[t] = tgt[e];
    }
    __syncthreads();
    int w = t >> 6, lane = t & 63, q = lane >> 4, m = lane & 15;
    int arow = w * 16 + m;
    int g = tgtS[arow], s = srcS[arow];

    // A fragments: lane holds A[m][k=q*8+j] for each K-chunk of 32
    short8 afr[9];
    {
        const short8* hg = (const short8*)(h_bf + (size_t)g * 128);
        const short8* hs = (const short8*)(h_bf + (size_t)s * 128);
        #pragma unroll
        for (int c = 0; c < 4; ++c) { afr[c] = hg[c * 4 + q]; afr[4 + c] = hs[c * 4 + q]; }
        float uv[8];
        if (q < 3) {
            #pragma unroll
            for (int j = 0; j < 8; ++j) {
                int ku = q * 8 + j;
                uv[j] = u[(size_t)g * 25 + ku] - u[(size_t)s * 25 + ku];
            }
        } else {
            uv[0] = u[(size_t)g * 25 + 24] - u[(size_t)s * 25 + 24];
            uv[1] = posx[g] - posx[s];
            uv[2] = post[g];
            uv[3] = uv[4] = uv[5] = uv[6] = uv[7] = 0.f;
        }
        short8 a8;
        #pragma unroll
        for (int j = 0; j < 8; ++j) a8[j] = (short)f2bf(uv[j]);
        afr[8] = a8;
    }

    // GEMM1: K=288 (9 chunks), N=128 (8 tiles)
    floatx4 acc[8] = {};
    #pragma unroll
    for (int c = 0; c < 9; ++c) {
        const short8* Bp = (const short8*)(W1p) + (size_t)(c * 8) * 64 + lane;
        #pragma unroll
        for (int t8 = 0; t8 < 8; ++t8) {
            short8 b = Bp[t8 * 64];
            acc[t8] = __builtin_amdgcn_mfma_f32_16x16x32_bf16(afr[c], b, acc[t8], 0, 0, 0);
        }
    }
    // epilogue 1: bias+swish, round-trip through LDS (C-layout -> A-layout)
    #pragma unroll
    for (int t8 = 0; t8 < 8; ++t8) {
        float bv = b1[t8 * 16 + m];
        #pragma unroll
        for (int r = 0; r < 4; ++r)
            Ms[(w * 16 + q * 4 + r) * 136 + t8 * 16 + m] = f2bf(swishf(acc[t8][r] + bv));
    }
    __syncthreads();
    short8 a2[4];
    #pragma unroll
    for (int c = 0; c < 4; ++c)
        a2[c] = *(const short8*)(&Ms[(w * 16 + m) * 136 + c * 32 + q * 8]);

    // GEMM2: K=128 (4 chunks)
    floatx4 acc2[8] = {};
    #pragma unroll
    for (int c = 0; c < 4; ++c) {
        const short8* Bp = (const short8*)(W2p) + (size_t)(c * 8) * 64 + lane;
        #pragma unroll
        for (int t8 = 0; t8 < 8; ++t8) {
            short8 b = Bp[t8 * 64];
            acc2[t8] = __builtin_amdgcn_mfma_f32_16x16x32_bf16(a2[c], b, acc2[t8], 0, 0, 0);
        }
    }
    if (CSR) {
        __syncthreads();
        #pragma unroll
        for (int t8 = 0; t8 < 8; ++t8) {
            float bv = b2[t8 * 16 + m];
            #pragma unroll
            for (int r = 0; r < 4; ++r)
                Ms[(w * 16 + q * 4 + r) * 136 + t8 * 16 + m] = f2bf(swishf(acc2[t8][r] + bv));
        }
        __syncthreads();
        int r2 = lane >> 2, cb = (lane & 3) * 32;
        const unsigned short* sp = &Ms[(w * 16 + r2) * 136 + cb];
        unsigned short* dp = msg + (size_t)(e0 + w * 16 + r2) * 128 + cb;
        #pragma unroll
        for (int k = 0; k < 4; ++k)
            *(short8*)(dp + k * 8) = *(const short8*)(sp + k * 8);
    } else {
        #pragma unroll
        for (int t8 = 0; t8 < 8; ++t8) {
            float bv = b2[t8 * 16 + m];
            #pragma unroll
            for (int r = 0; r < 4; ++r) {
                int rr = w * 16 + q * 4 + r;
                atomicAdd(&agg[(size_t)tgtS[rr] * 128 + t8 * 16 + m],
                          swishf(acc2[t8][r] + bv));
            }
        }
    }
}

// ---------------------------------------------------------------------------
// CSR gather: one wave per node, sum its contiguous msg slots
__global__ __launch_bounds__(256) void agg_kernel(const unsigned short* __restrict__ msg,
                                                  const int* __restrict__ rowptr,
                                                  float* __restrict__ agg) {
    int n = blockIdx.x * 4 + (threadIdx.x >> 6);
    int lane = threadIdx.x & 63;
    int s = rowptr[n], e = rowptr[n + 1];
    float a0 = 0.f, a1 = 0.f;
    for (int i = s; i < e; ++i) {
        unsigned v = *(const unsigned*)(msg + (size_t)i * 128 + lane * 2);
        a0 += bf2f((unsigned short)(v & 0xffffu));
        a1 += bf2f((unsigned short)(v >> 16));
    }
    float* dst = agg + (size_t)n * 128 + lane * 2;
    dst[0] = a0; dst[1] = a1;
}

// ---------------------------------------------------------------------------
// MFMA update MLP: h += swish(swish([h, agg/cnt, post]@Wu1+bu1)@Wu2+bu2)
__global__ __launch_bounds__(256) void update_kernel(
    float* __restrict__ h, const unsigned short* __restrict__ h_bf,
    const float* __restrict__ agg, const int* __restrict__ deg,
    const float* __restrict__ post,
    const unsigned short* __restrict__ W1p, const float* __restrict__ b1,
    const unsigned short* __restrict__ W2p, const float* __restrict__ b2)
{
    __shared__ unsigned short Ms[64 * 136];
    int t = threadIdx.x;
    int n0 = blockIdx.x * 64;
    int w = t >> 6, lane = t & 63, q = lane >> 4, m = lane & 15;
    int n = n0 + w * 16 + m;

    short8 afr[9];
    {
        const short8* hn = (const short8*)(h_bf + (size_t)n * 128);
        #pragma unroll
        for (int c = 0; c < 4; ++c) afr[c] = hn[c * 4 + q];
        float ic = 1.0f / fmaxf((float)deg[n], 1.0f);
        #pragma unroll
        for (int c = 0; c < 4; ++c) {
            const float* ap = agg + (size_t)n * 128 + c * 32 + q * 8;
            short8 a;
            #pragma unroll
            for (int j = 0; j < 8; ++j) a[j] = (short)f2bf(ap[j] * ic);
            afr[4 + c] = a;
        }
        short8 a8;
        #pragma unroll
        for (int j = 0; j < 8; ++j) a8[j] = 0;
        if (q == 0) a8[0] = (short)f2bf(post[n]);  // k=256
        afr[8] = a8;
    }

    floatx4 acc[8] = {};
    #pragma unroll
    for (int c = 0; c < 9; ++c) {
        const short8* Bp = (const short8*)(W1p) + (size_t)(c * 8) * 64 + lane;
        #pragma unroll
        for (int t8 = 0; t8 < 8; ++t8) {
            short8 b = Bp[t8 * 64];
            acc[t8] = __builtin_amdgcn_mfma_f32_16x16x32_bf16(afr[c], b, acc[t8], 0, 0, 0);
        }
    }
    #pragma unroll
    for (int t8 = 0; t8 < 8; ++t8) {
        float bv = b1[t8 * 16 + m];
        #pragma unroll
        for (int r = 0; r < 4; ++r)
            Ms[(w * 16 + q * 4 + r) * 136 + t8 * 16 + m] = f2bf(swishf(acc[t8][r] + bv));
    }
    __syncthreads();
    short8 a2[4];
    #pragma unroll
    for (int c = 0; c < 4; ++c)
        a2[c] = *(const short8*)(&Ms[(w * 16 + m) * 136 + c * 32 + q * 8]);

    floatx4 acc2[8] = {};
    #pragma unroll
    for (int c = 0; c < 4; ++c) {
        const short8* Bp = (const short8*)(W2p) + (size_t)(c * 8) * 64 + lane;
        #pragma unroll
        for (int t8 = 0; t8 < 8; ++t8) {
            short8 b = Bp[t8 * 64];
            acc2[t8] = __builtin_amdgcn_mfma_f32_16x16x32_bf16(a2[c], b, acc2[t8], 0, 0, 0);
        }
    }
    #pragma unroll
    for (int t8 = 0; t8 < 8; ++t8) {
        float bv = b2[t8 * 16 + m];
        #pragma unroll
        for (int r = 0; r < 4; ++r) {
            size_t idx = (size_t)(n0 + w * 16 + q * 4 + r) * 128 + t8 * 16 + m;
            h[idx] += swishf(acc2[t8][r] + bv);
        }
    }
}

// ---------------------------------------------------------------------------
__global__ __launch_bounds__(128) void stats_kernel(const float* __restrict__ h,
                                                    float* __restrict__ stats) {
    int c = threadIdx.x;
    int n0 = blockIdx.x * 64;
    int b = n0 >> 12;
    float s = 0.f, s2 = 0.f;
    for (int i = 0; i < 64; ++i) {
        float v = h[(size_t)(n0 + i) * 128 + c];
        s += v; s2 += v * v;
    }
    atomicAdd(&stats[b * 128 + c], s);
    atomicAdd(&stats[(NB + b) * 128 + c], s2);
}

__global__ __launch_bounds__(256) void norm_kernel(float* __restrict__ h,
                                                   unsigned short* __restrict__ h_bf,
                                                   const float* __restrict__ stats) {
    size_t idx = (size_t)blockIdx.x * 256 + threadIdx.x;
    int n = (int)(idx >> 7), c = (int)(idx & 127);
    int b = n >> 12;
    float mean = stats[b * 128 + c] * (1.f / 4096.f);
    float var = stats[(NB + b) * 128 + c] * (1.f / 4096.f) - mean * mean;
    float v = h[idx];
    float r = (v - mean) * rsqrtf(var + 1e-5f);
    h[idx] = r;
    h_bf[idx] = f2bf(r);
}

// ---------------------------------------------------------------------------
__global__ __launch_bounds__(64) void conv_kernel(
    const float* __restrict__ h, const float* __restrict__ u,
    const float* __restrict__ Wc1, const float* __restrict__ bc1,
    const float* __restrict__ Wc2, const float* __restrict__ bc2,
    float* __restrict__ out)
{
    __shared__ float hs[128];
    __shared__ float c1[8 * 38];
    int n = blockIdx.x;
    int t = threadIdx.x;
    hs[t] = h[(size_t)n * 128 + t];
    hs[t + 64] = h[(size_t)n * 128 + t + 64];
    __syncthreads();
    for (int idx = t; idx < 304; idx += 64) {
        int o = idx / 38, p = idx % 38;
        float s = bc1[o];
        #pragma unroll
        for (int k = 0; k < 16; ++k) s += hs[p * 3 + k] * Wc1[o * 16 + k];
        c1[o * 38 + p] = swishf(s);
    }
    __syncthreads();
    if (t < TW) {
        float s = bc2[0];
        #pragma unroll
        for (int o = 0; o < 8; ++o)
            for (int k = 0; k < 14; ++k)
                s += c1[o * 38 + t + k] * Wc2[o * 14 + k];
        float dt_cum = (float)(t + 1) * (4.0f / 250.0f);
        out[n * TW + t] = u[n * 25 + 24] + dt_cum * s;
    }
}

// ---------------------------------------------------------------------------
extern "C" void kernel_launch(void* const* d_in, const int* in_sizes, int n_in,
                              void* d_out, int out_size, void* d_ws, size_t ws_size,
                              hipStream_t stream)
{
    const float* u   = (const float*)d_in[0];
    const float* pos = (const float*)d_in[1];
    const int*   ei  = (const int*)d_in[2];
    const float* We1 = (const float*)d_in[4];
    const float* be1 = (const float*)d_in[5];
    const float* We2 = (const float*)d_in[6];
    const float* be2 = (const float*)d_in[7];
    const float* Wm1 = (const float*)d_in[8];
    const float* bm1 = (const float*)d_in[9];
    const float* Wm2 = (const float*)d_in[10];
    const float* bm2 = (const float*)d_in[11];
    const float* Wu1 = (const float*)d_in[12];
    const float* bu1 = (const float*)d_in[13];
    const float* Wu2 = (const float*)d_in[14];
    const float* bu2 = (const float*)d_in[15];
    const float* Wc1 = (const float*)d_in[16];
    const float* bc1 = (const float*)d_in[17];
    const float* Wc2 = (const float*)d_in[18];
    const float* bc2 = (const float*)d_in[19];
    float* out = (float*)d_out;

    char* base = (char*)d_ws;
    size_t off = 0;
    auto alloc = [&](size_t bytes) -> char* {
        char* r = base + off;
        off = (off + bytes + 511) & ~(size_t)511;
        return r;
    };
    float*          h      = (float*)alloc((size_t)N_NODES * 128 * 4);
    unsigned short* h_bf   = (unsigned short*)alloc((size_t)N_NODES * 128 * 2);
    float*          agg    = (float*)alloc((size_t)N_NODES * 128 * 4);
    float*          posx   = (float*)alloc(N_NODES * 4);
    float*          post   = (float*)alloc(N_NODES * 4);
    float*          stats  = (float*)alloc(2 * NB * 128 * 4);
    int*            deg    = (int*)alloc(N_NODES * 4);
    int*            rowptr = (int*)alloc((N_NODES + 1) * 4);
    int*            cursor = (int*)alloc(N_NODES * 4);
    int*            perm   = (int*)alloc((size_t)N_EDGES * 4);
    unsigned short* Wm1p   = (unsigned short*)alloc((size_t)6 * 9 * 4096 * 2);
    unsigned short* Wm2p   = (unsigned short*)alloc((size_t)6 * 4 * 4096 * 2);
    unsigned short* Wu1p   = (unsigned short*)alloc((size_t)6 * 9 * 4096 * 2);
    unsigned short* Wu2p   = (unsigned short*)alloc((size_t)6 * 4 * 4096 * 2);
    size_t need_nocsr = off;
    unsigned short* msg    = (unsigned short*)alloc((size_t)N_EDGES * 128 * 2);
    bool csr = (off <= ws_size);
    (void)need_nocsr;

    const int* srcp = ei;
    const int* tgtp = ei + N_EDGES;

    init_kernel<<<N_NODES / 256, 256, 0, stream>>>(pos, posx, post);
    hipMemsetAsync(deg, 0, N_NODES * sizeof(int), stream);
    deg_kernel<<<N_EDGES / 256, 256, 0, stream>>>(tgtp, deg);
    if (csr) {
        scan_kernel<<<1, 1024, 0, stream>>>(deg, rowptr, cursor);
        scatter_kernel<<<N_EDGES / 256, 256, 0, stream>>>(tgtp, cursor, perm);
    }
    encoder_kernel<<<N_NODES / 64, 256, 0, stream>>>(u, posx, post, We1, be1, We2, be2, h, h_bf);

    // pack weights (once per launch)
    {
        int tot1 = 6 * 9 * 512;  // Kc=9
        int tot2 = 6 * 4 * 512;  // Kc=4
        pack_kernel<<<(tot1 + 255) / 256, 256, 0, stream>>>(Wm1, Wm1p, 283, 9, tot1);
        pack_kernel<<<(tot2 + 255) / 256, 256, 0, stream>>>(Wm2, Wm2p, 128, 4, tot2);
        pack_kernel<<<(tot1 + 255) / 256, 256, 0, stream>>>(Wu1, Wu1p, 257, 9, tot1);
        pack_kernel<<<(tot2 + 255) / 256, 256, 0, stream>>>(Wu2, Wu2p, 128, 4, tot2);
    }

    for (int l = 0; l < 6; ++l) {
        const unsigned short* W1p = Wm1p + (size_t)l * 9 * 4096;
        const unsigned short* W2p = Wm2p + (size_t)l * 4 * 4096;
        if (csr) {
            message_kernel<1><<<N_EDGES / 64, 256, 0, stream>>>(
                h_bf, u, posx, post, srcp, tgtp, perm,
                W1p, bm1 + l * 128, W2p, bm2 + l * 128, msg, agg);
            agg_kernel<<<N_NODES / 4, 256, 0, stream>>>(msg, rowptr, agg);
        } else {
            hipMemsetAsync(agg, 0, (size_t)N_NODES * 128 * sizeof(float), stream);
            message_kernel<0><<<N_EDGES / 64, 256, 0, stream>>>(
                h_bf, u, posx, post, srcp, tgtp, perm,
                W1p, bm1 + l * 128, W2p, bm2 + l * 128, msg, agg);
        }
        update_kernel<<<N_NODES / 64, 256, 0, stream>>>(
            h, h_bf, agg, deg, post,
            Wu1p + (size_t)l * 9 * 4096, bu1 + l * 128,
            Wu2p + (size_t)l * 4 * 4096, bu2 + l * 128);
        hipMemsetAsync(stats, 0, 2 * NB * 128 * sizeof(float), stream);
        stats_kernel<<<N_NODES / 64, 128, 0, stream>>>(h, stats);
        norm_kernel<<<(N_NODES * 128) / 256, 256, 0, stream>>>(h, h_bf, stats);
    }

    conv_kernel<<<N_NODES, 64, 0, stream>>>(h, u, Wc1, bc1, Wc2, bc2, out);
}

// Round 3
// 931.592 us; speedup vs baseline: 4.7760x; 1.1439x over previous
//
#include <hip/hip_runtime.h>
#include <stdint.h>

#define N_NODES 32768
#define N_EDGES 262144
#define NB 8
#define TW 25

typedef __attribute__((ext_vector_type(8))) short short8;
typedef __attribute__((ext_vector_type(4))) float floatx4;

__device__ __forceinline__ float swishf(float x) { return x / (1.0f + __expf(-x)); }

__device__ __forceinline__ unsigned short f2bf(float x) {
    union { float f; unsigned u; } v; v.f = x;
    unsigned r = v.u + 0x7FFFu + ((v.u >> 16) & 1u);
    return (unsigned short)(r >> 16);
}
__device__ __forceinline__ float bf2f(unsigned short b) {
    union { unsigned u; float f; } v; v.u = ((unsigned)b) << 16; return v.f;
}

// ---------------------------------------------------------------------------
__global__ void init_kernel(const float* __restrict__ pos,
                            float* __restrict__ posx, float* __restrict__ post) {
    int i = blockIdx.x * 256 + threadIdx.x;
    if (i < N_NODES) {
        post[i] = pos[i * 2 + 0] * 0.25f;
        posx[i] = pos[i * 2 + 1] * 0.0625f;
    }
}

__global__ void deg_kernel(const int* __restrict__ tgt, int* __restrict__ deg) {
    int i = blockIdx.x * 256 + threadIdx.x;
    if (i < N_EDGES) atomicAdd(&deg[tgt[i]], 1);
}

__global__ __launch_bounds__(1024) void scan_kernel(const int* __restrict__ deg,
                                                    int* __restrict__ rowptr,
                                                    int* __restrict__ cursor) {
    __shared__ int ps[1024];
    int t = threadIdx.x;
    int base = t * 32;
    int tot = 0;
    for (int i = 0; i < 32; ++i) tot += deg[base + i];
    ps[t] = tot;
    __syncthreads();
    for (int off = 1; off < 1024; off <<= 1) {
        int v = (t >= off) ? ps[t - off] : 0;
        __syncthreads();
        ps[t] += v;
        __syncthreads();
    }
    int run = ps[t] - tot;
    for (int i = 0; i < 32; ++i) {
        rowptr[base + i] = run;
        cursor[base + i] = run;
        run += deg[base + i];
    }
    if (t == 1023) rowptr[N_NODES] = run;
}

__global__ void scatter_kernel(const int* __restrict__ tgt, int* __restrict__ cursor,
                               int* __restrict__ perm) {
    int i = blockIdx.x * 256 + threadIdx.x;
    if (i < N_EDGES) {
        int p = atomicAdd(&cursor[tgt[i]], 1);
        perm[p] = i;
    }
}

// ---------------------------------------------------------------------------
// Pack weight into MFMA B-frag order (see round-2 comment).
__global__ __launch_bounds__(256) void pack_kernel(const float* __restrict__ W,
                                                   unsigned short* __restrict__ Wp,
                                                   int Kreal, int Kc, int total) {
    int id = blockIdx.x * 256 + threadIdx.x;
    if (id >= total) return;
    int lane = id & 63;
    int t8 = (id >> 6) & 7;
    int rest = id >> 9;
    int c = rest % Kc;
    int l = rest / Kc;
    int n = t8 * 16 + (lane & 15);
    int kb = c * 32 + (lane >> 4) * 8;
    short8 v;
    #pragma unroll
    for (int j = 0; j < 8; ++j) {
        int k = kb + j;
        float x = (k < Kreal) ? W[((size_t)l * Kreal + k) * 128 + n] : 0.f;
        v[j] = (short)f2bf(x);
    }
    *(short8*)(Wp + (size_t)id * 8) = v;
}

// ---------------------------------------------------------------------------
__global__ __launch_bounds__(256) void encoder_kernel(
    const float* __restrict__ u, const float* __restrict__ posx,
    const float* __restrict__ post,
    const float* __restrict__ We1, const float* __restrict__ be1,
    const float* __restrict__ We2, const float* __restrict__ be2,
    float* __restrict__ h, unsigned short* __restrict__ h_bf)
{
    __shared__ __align__(16) float As[64 * 36];
    __shared__ __align__(16) float Ws[32 * 128];
    __shared__ __align__(16) float Ms[64 * 128];

    int t = threadIdx.x;
    int n0 = blockIdx.x * 64;
    int rg = t >> 5, cg = t & 31;

    float acc[8][4] = {};
    {
        int kk = t >> 3, cb = (t & 7) * 16;
        #pragma unroll
        for (int j = 0; j < 4; ++j) {
            float4 w = make_float4(0.f, 0.f, 0.f, 0.f);
            if (kk < 27) w = *(const float4*)&We1[kk * 128 + cb + j * 4];
            *(float4*)&Ws[kk * 128 + cb + j * 4] = w;
        }
        int el = t >> 2, kb = (t & 3) * 8, n = n0 + el;
        float v[8];
        #pragma unroll
        for (int j = 0; j < 8; ++j) {
            int k = kb + j;
            float x = 0.f;
            if (k < 25) x = u[n * 25 + k];
            else if (k == 25) x = posx[n];
            else if (k == 26) x = post[n];
            v[j] = x;
        }
        #pragma unroll
        for (int j = 0; j < 8; j += 4)
            *(float4*)&As[el * 36 + kb + j] = make_float4(v[j], v[j+1], v[j+2], v[j+3]);
        __syncthreads();
        #pragma unroll 4
        for (int kk2 = 0; kk2 < 32; ++kk2) {
            float4 b = *(const float4*)&Ws[kk2 * 128 + cg * 4];
            float a[8];
            #pragma unroll
            for (int i = 0; i < 8; ++i) a[i] = As[(rg * 8 + i) * 36 + kk2];
            #pragma unroll
            for (int i = 0; i < 8; ++i) {
                acc[i][0] += a[i] * b.x; acc[i][1] += a[i] * b.y;
                acc[i][2] += a[i] * b.z; acc[i][3] += a[i] * b.w;
            }
        }
        __syncthreads();
    }
    {
        float4 b1 = *(const float4*)&be1[cg * 4];
        #pragma unroll
        for (int i = 0; i < 8; ++i) {
            float4 m;
            m.x = swishf(acc[i][0] + b1.x);
            m.y = swishf(acc[i][1] + b1.y);
            m.z = swishf(acc[i][2] + b1.z);
            m.w = swishf(acc[i][3] + b1.w);
            *(float4*)&Ms[(rg * 8 + i) * 128 + cg * 4] = m;
        }
        __syncthreads();
    }
    float acc2[8][4] = {};
    for (int k0 = 0; k0 < 128; k0 += 32) {
        int kk = t >> 3, cb = (t & 7) * 16;
        #pragma unroll
        for (int j = 0; j < 4; ++j)
            *(float4*)&Ws[kk * 128 + cb + j * 4] =
                *(const float4*)&We2[(k0 + kk) * 128 + cb + j * 4];
        __syncthreads();
        #pragma unroll 4
        for (int kk2 = 0; kk2 < 32; ++kk2) {
            float4 b = *(const float4*)&Ws[kk2 * 128 + cg * 4];
            float a[8];
            #pragma unroll
            for (int i = 0; i < 8; ++i) a[i] = Ms[(rg * 8 + i) * 128 + (k0 + kk2)];
            #pragma unroll
            for (int i = 0; i < 8; ++i) {
                acc2[i][0] += a[i] * b.x; acc2[i][1] += a[i] * b.y;
                acc2[i][2] += a[i] * b.z; acc2[i][3] += a[i] * b.w;
            }
        }
        __syncthreads();
    }
    {
        float4 b2 = *(const float4*)&be2[cg * 4];
        #pragma unroll
        for (int i = 0; i < 8; ++i) {
            int n = n0 + rg * 8 + i;
            float4 o;
            o.x = swishf(acc2[i][0] + b2.x);
            o.y = swishf(acc2[i][1] + b2.y);
            o.z = swishf(acc2[i][2] + b2.z);
            o.w = swishf(acc2[i][3] + b2.w);
            *(float4*)&h[(size_t)n * 128 + cg * 4] = o;
            unsigned short* hb = h_bf + (size_t)n * 128 + cg * 4;
            uint2 pk;
            pk.x = (unsigned)f2bf(o.x) | ((unsigned)f2bf(o.y) << 16);
            pk.y = (unsigned)f2bf(o.z) | ((unsigned)f2bf(o.w) << 16);
            *(uint2*)hb = pk;
        }
    }
}

// ---------------------------------------------------------------------------
// Message MLP, restructured:
//  - block = 64 tgt-sorted edges (perm), 4 waves
//  - A (64 x 288 bf16) staged in LDS once (stride 296 for bank spread)
//  - wave w owns cols [32w,32w+32): B-traffic 104 KB/block (was 416)
//  - GEMM1 -> Ms (LDS, reuse) -> GEMM2 -> Cs (LDS bf16) -> in-block
//    equal-tgt run reduction -> fp32 atomics into agg (no msg stream)
__global__ __launch_bounds__(256, 4) void message_kernel(
    const unsigned short* __restrict__ h_bf, const float* __restrict__ u,
    const float* __restrict__ posx, const float* __restrict__ post,
    const int* __restrict__ src, const int* __restrict__ tgt,
    const int* __restrict__ perm,
    const unsigned short* __restrict__ W1p, const float* __restrict__ b1,
    const unsigned short* __restrict__ W2p, const float* __restrict__ b2,
    float* __restrict__ agg)
{
    __shared__ __align__(16) unsigned short SH[64 * 296];  // 37888 B
    __shared__ int srcS[64], tgtS[64];
    unsigned short* Msh = SH;          // 64 x 136 bf16 (17408 B)
    unsigned short* Cs  = SH + 9216;   // byte 18432: 64 x 132 bf16 (16896 B)

    int t = threadIdx.x;
    int e0 = blockIdx.x * 64;
    if (t < 64) {
        int e = perm[e0 + t];
        srcS[t] = src[e]; tgtS[t] = tgt[e];
    }
    __syncthreads();

    // ---- stage A into LDS
    {
        int r = t & 63, cseg = t >> 6;
        int g = tgtS[r], s = srcS[r];
        const short8* hg = (const short8*)(h_bf + (size_t)g * 128);
        const short8* hs = (const short8*)(h_bf + (size_t)s * 128);
        #pragma unroll
        for (int j = 0; j < 4; ++j) {
            int chunk = cseg * 4 + j;  // 0..15
            *(short8*)(SH + r * 296 + chunk * 8)       = hg[chunk];
            *(short8*)(SH + r * 296 + 128 + chunk * 8) = hs[chunk];
        }
        int r2 = t >> 2, part = t & 3;
        int gg = tgtS[r2], ss = srcS[r2];
        unsigned short* dst = SH + r2 * 296 + 256 + part * 8;
        if (part < 3) {
            #pragma unroll
            for (int j = 0; j < 8; ++j) {
                int k = part * 8 + j;
                dst[j] = f2bf(u[(size_t)gg * 25 + k] - u[(size_t)ss * 25 + k]);
            }
        } else {
            dst[0] = f2bf(u[(size_t)gg * 25 + 24] - u[(size_t)ss * 25 + 24]);
            dst[1] = f2bf(posx[gg] - posx[ss]);
            dst[2] = f2bf(post[gg]);
            dst[3] = 0; dst[4] = 0; dst[5] = 0; dst[6] = 0; dst[7] = 0;
        }
    }
    __syncthreads();

    int w = t >> 6, lane = t & 63, q = lane >> 4, m = lane & 15;
    int t80 = 2 * w, t81 = 2 * w + 1;

    // ---- GEMM1: K=288 (9 chunks), wave's 2 N-tiles, 4 M-groups
    floatx4 acc0[4] = {}, acc1[4] = {};
    #pragma unroll
    for (int c = 0; c < 9; ++c) {
        short8 b0 = *(const short8*)(W1p + ((size_t)(c * 8 + t80) * 64 + lane) * 8);
        short8 b1f = *(const short8*)(W1p + ((size_t)(c * 8 + t81) * 64 + lane) * 8);
        #pragma unroll
        for (int g2 = 0; g2 < 4; ++g2) {
            short8 a = *(const short8*)(SH + (g2 * 16 + m) * 296 + c * 32 + q * 8);
            acc0[g2] = __builtin_amdgcn_mfma_f32_16x16x32_bf16(a, b0, acc0[g2], 0, 0, 0);
            acc1[g2] = __builtin_amdgcn_mfma_f32_16x16x32_bf16(a, b1f, acc1[g2], 0, 0, 0);
        }
    }
    __syncthreads();  // A region dead; safe to write Ms

    // ---- epilogue 1 -> Ms
    {
        float bv0 = b1[t80 * 16 + m], bv1 = b1[t81 * 16 + m];
        #pragma unroll
        for (int g2 = 0; g2 < 4; ++g2) {
            #pragma unroll
            for (int r = 0; r < 4; ++r) {
                int row = g2 * 16 + q * 4 + r;
                Msh[row * 136 + t80 * 16 + m] = f2bf(swishf(acc0[g2][r] + bv0));
                Msh[row * 136 + t81 * 16 + m] = f2bf(swishf(acc1[g2][r] + bv1));
            }
        }
    }
    __syncthreads();

    // ---- GEMM2: K=128 (4 chunks)
    floatx4 acc2a[4] = {}, acc2b[4] = {};
    #pragma unroll
    for (int c = 0; c < 4; ++c) {
        short8 b0 = *(const short8*)(W2p + ((size_t)(c * 8 + t80) * 64 + lane) * 8);
        short8 b1f = *(const short8*)(W2p + ((size_t)(c * 8 + t81) * 64 + lane) * 8);
        #pragma unroll
        for (int g2 = 0; g2 < 4; ++g2) {
            short8 a = *(const short8*)(Msh + (g2 * 16 + m) * 136 + c * 32 + q * 8);
            acc2a[g2] = __builtin_amdgcn_mfma_f32_16x16x32_bf16(a, b0, acc2a[g2], 0, 0, 0);
            acc2b[g2] = __builtin_amdgcn_mfma_f32_16x16x32_bf16(a, b1f, acc2b[g2], 0, 0, 0);
        }
    }
    // ---- epilogue 2 -> Cs (disjoint from Ms; no barrier needed before writes)
    {
        float bv0 = b2[t80 * 16 + m], bv1 = b2[t81 * 16 + m];
        #pragma unroll
        for (int g2 = 0; g2 < 4; ++g2) {
            #pragma unroll
            for (int r = 0; r < 4; ++r) {
                int row = g2 * 16 + q * 4 + r;
                Cs[row * 132 + t80 * 16 + m] = f2bf(swishf(acc2a[g2][r] + bv0));
                Cs[row * 132 + t81 * 16 + m] = f2bf(swishf(acc2b[g2][r] + bv1));
            }
        }
    }
    __syncthreads();

    // ---- in-block reduction over equal-tgt runs -> atomics into agg
    {
        int cp = t & 63;          // column pair: cols 2cp, 2cp+1
        int quarter = t >> 6;     // rows quarter*16 .. +15
        float a0 = 0.f, a1 = 0.f;
        int prev = tgtS[quarter * 16];
        #pragma unroll 4
        for (int i = 0; i < 16; ++i) {
            int row = quarter * 16 + i;
            int tg = tgtS[row];
            if (tg != prev) {
                atomicAdd(&agg[(size_t)prev * 128 + 2 * cp], a0);
                atomicAdd(&agg[(size_t)prev * 128 + 2 * cp + 1], a1);
                a0 = a1 = 0.f;
                prev = tg;
            }
            unsigned v = *(const unsigned*)(Cs + row * 132 + cp * 2);
            a0 += bf2f((unsigned short)(v & 0xffffu));
            a1 += bf2f((unsigned short)(v >> 16));
        }
        atomicAdd(&agg[(size_t)prev * 128 + 2 * cp], a0);
        atomicAdd(&agg[(size_t)prev * 128 + 2 * cp + 1], a1);
    }
}

// ---------------------------------------------------------------------------
// Update MLP + fused batch-stats accumulation.
__global__ __launch_bounds__(256) void update_kernel(
    float* __restrict__ h, const unsigned short* __restrict__ h_bf,
    const float* __restrict__ agg, const int* __restrict__ deg,
    const float* __restrict__ post,
    const unsigned short* __restrict__ W1p, const float* __restrict__ b1,
    const unsigned short* __restrict__ W2p, const float* __restrict__ b2,
    float* __restrict__ stats)
{
    __shared__ unsigned short Ms[64 * 136];
    int t = threadIdx.x;
    int n0 = blockIdx.x * 64;
    int w = t >> 6, lane = t & 63, q = lane >> 4, m = lane & 15;
    int n = n0 + w * 16 + m;

    short8 afr[9];
    {
        const short8* hn = (const short8*)(h_bf + (size_t)n * 128);
        #pragma unroll
        for (int c = 0; c < 4; ++c) afr[c] = hn[c * 4 + q];
        float ic = 1.0f / fmaxf((float)deg[n], 1.0f);
        #pragma unroll
        for (int c = 0; c < 4; ++c) {
            const float* ap = agg + (size_t)n * 128 + c * 32 + q * 8;
            short8 a;
            #pragma unroll
            for (int j = 0; j < 8; ++j) a[j] = (short)f2bf(ap[j] * ic);
            afr[4 + c] = a;
        }
        short8 a8;
        #pragma unroll
        for (int j = 0; j < 8; ++j) a8[j] = 0;
        if (q == 0) a8[0] = (short)f2bf(post[n]);  // k=256
        afr[8] = a8;
    }

    floatx4 acc[8] = {};
    #pragma unroll
    for (int c = 0; c < 9; ++c) {
        const short8* Bp = (const short8*)(W1p) + (size_t)(c * 8) * 64 + lane;
        #pragma unroll
        for (int t8 = 0; t8 < 8; ++t8) {
            short8 b = Bp[t8 * 64];
            acc[t8] = __builtin_amdgcn_mfma_f32_16x16x32_bf16(afr[c], b, acc[t8], 0, 0, 0);
        }
    }
    #pragma unroll
    for (int t8 = 0; t8 < 8; ++t8) {
        float bv = b1[t8 * 16 + m];
        #pragma unroll
        for (int r = 0; r < 4; ++r)
            Ms[(w * 16 + q * 4 + r) * 136 + t8 * 16 + m] = f2bf(swishf(acc[t8][r] + bv));
    }
    __syncthreads();
    short8 a2[4];
    #pragma unroll
    for (int c = 0; c < 4; ++c)
        a2[c] = *(const short8*)(&Ms[(w * 16 + m) * 136 + c * 32 + q * 8]);

    floatx4 acc2[8] = {};
    #pragma unroll
    for (int c = 0; c < 4; ++c) {
        const short8* Bp = (const short8*)(W2p) + (size_t)(c * 8) * 64 + lane;
        #pragma unroll
        for (int t8 = 0; t8 < 8; ++t8) {
            short8 b = Bp[t8 * 64];
            acc2[t8] = __builtin_amdgcn_mfma_f32_16x16x32_bf16(a2[c], b, acc2[t8], 0, 0, 0);
        }
    }
    int bidx = n0 >> 12;
    #pragma unroll
    for (int t8 = 0; t8 < 8; ++t8) {
        float bv = b2[t8 * 16 + m];
        float s = 0.f, s2 = 0.f;
        #pragma unroll
        for (int r = 0; r < 4; ++r) {
            size_t idx = (size_t)(n0 + w * 16 + q * 4 + r) * 128 + t8 * 16 + m;
            float hv = h[idx] + swishf(acc2[t8][r] + bv);
            h[idx] = hv;
            s += hv; s2 += hv * hv;
        }
        // reduce across q (wave rows) -> q==0 lanes hold 16-row col sums
        s  += __shfl_xor(s, 16);  s  += __shfl_xor(s, 32);
        s2 += __shfl_xor(s2, 16); s2 += __shfl_xor(s2, 32);
        if (q == 0) {
            atomicAdd(&stats[bidx * 128 + t8 * 16 + m], s);
            atomicAdd(&stats[(NB + bidx) * 128 + t8 * 16 + m], s2);
        }
    }
}

// ---------------------------------------------------------------------------
__global__ __launch_bounds__(256) void norm_kernel(float* __restrict__ h,
                                                   unsigned short* __restrict__ h_bf,
                                                   const float* __restrict__ stats) {
    size_t idx = (size_t)blockIdx.x * 256 + threadIdx.x;
    int n = (int)(idx >> 7), c = (int)(idx & 127);
    int b = n >> 12;
    float mean = stats[b * 128 + c] * (1.f / 4096.f);
    float var = stats[(NB + b) * 128 + c] * (1.f / 4096.f) - mean * mean;
    float v = h[idx];
    float r = (v - mean) * rsqrtf(var + 1e-5f);
    h[idx] = r;
    h_bf[idx] = f2bf(r);
}

// ---------------------------------------------------------------------------
__global__ __launch_bounds__(64) void conv_kernel(
    const float* __restrict__ h, const float* __restrict__ u,
    const float* __restrict__ Wc1, const float* __restrict__ bc1,
    const float* __restrict__ Wc2, const float* __restrict__ bc2,
    float* __restrict__ out)
{
    __shared__ float hs[128];
    __shared__ float c1[8 * 38];
    int n = blockIdx.x;
    int t = threadIdx.x;
    hs[t] = h[(size_t)n * 128 + t];
    hs[t + 64] = h[(size_t)n * 128 + t + 64];
    __syncthreads();
    for (int idx = t; idx < 304; idx += 64) {
        int o = idx / 38, p = idx % 38;
        float s = bc1[o];
        #pragma unroll
        for (int k = 0; k < 16; ++k) s += hs[p * 3 + k] * Wc1[o * 16 + k];
        c1[o * 38 + p] = swishf(s);
    }
    __syncthreads();
    if (t < TW) {
        float s = bc2[0];
        #pragma unroll
        for (int o = 0; o < 8; ++o)
            for (int k = 0; k < 14; ++k)
                s += c1[o * 38 + t + k] * Wc2[o * 14 + k];
        float dt_cum = (float)(t + 1) * (4.0f / 250.0f);
        out[n * TW + t] = u[n * 25 + 24] + dt_cum * s;
    }
}

// ---------------------------------------------------------------------------
extern "C" void kernel_launch(void* const* d_in, const int* in_sizes, int n_in,
                              void* d_out, int out_size, void* d_ws, size_t ws_size,
                              hipStream_t stream)
{
    const float* u   = (const float*)d_in[0];
    const float* pos = (const float*)d_in[1];
    const int*   ei  = (const int*)d_in[2];
    const float* We1 = (const float*)d_in[4];
    const float* be1 = (const float*)d_in[5];
    const float* We2 = (const float*)d_in[6];
    const float* be2 = (const float*)d_in[7];
    const float* Wm1 = (const float*)d_in[8];
    const float* bm1 = (const float*)d_in[9];
    const float* Wm2 = (const float*)d_in[10];
    const float* bm2 = (const float*)d_in[11];
    const float* Wu1 = (const float*)d_in[12];
    const float* bu1 = (const float*)d_in[13];
    const float* Wu2 = (const float*)d_in[14];
    const float* bu2 = (const float*)d_in[15];
    const float* Wc1 = (const float*)d_in[16];
    const float* bc1 = (const float*)d_in[17];
    const float* Wc2 = (const float*)d_in[18];
    const float* bc2 = (const float*)d_in[19];
    float* out = (float*)d_out;

    char* base = (char*)d_ws;
    size_t off = 0;
    auto alloc = [&](size_t bytes) -> char* {
        char* r = base + off;
        off = (off + bytes + 511) & ~(size_t)511;
        return r;
    };
    float*          h      = (float*)alloc((size_t)N_NODES * 128 * 4);
    unsigned short* h_bf   = (unsigned short*)alloc((size_t)N_NODES * 128 * 2);
    float*          agg    = (float*)alloc((size_t)N_NODES * 128 * 4);
    float*          posx   = (float*)alloc(N_NODES * 4);
    float*          post   = (float*)alloc(N_NODES * 4);
    float*          stats  = (float*)alloc(2 * NB * 128 * 4);
    int*            deg    = (int*)alloc(N_NODES * 4);
    int*            rowptr = (int*)alloc((N_NODES + 1) * 4);
    int*            cursor = (int*)alloc(N_NODES * 4);
    int*            perm   = (int*)alloc((size_t)N_EDGES * 4);
    unsigned short* Wm1p   = (unsigned short*)alloc((size_t)6 * 9 * 4096 * 2);
    unsigned short* Wm2p   = (unsigned short*)alloc((size_t)6 * 4 * 4096 * 2);
    unsigned short* Wu1p   = (unsigned short*)alloc((size_t)6 * 9 * 4096 * 2);
    unsigned short* Wu2p   = (unsigned short*)alloc((size_t)6 * 4 * 4096 * 2);
    (void)ws_size;

    const int* srcp = ei;
    const int* tgtp = ei + N_EDGES;

    init_kernel<<<N_NODES / 256, 256, 0, stream>>>(pos, posx, post);
    hipMemsetAsync(deg, 0, N_NODES * sizeof(int), stream);
    deg_kernel<<<N_EDGES / 256, 256, 0, stream>>>(tgtp, deg);
    scan_kernel<<<1, 1024, 0, stream>>>(deg, rowptr, cursor);
    scatter_kernel<<<N_EDGES / 256, 256, 0, stream>>>(tgtp, cursor, perm);
    encoder_kernel<<<N_NODES / 64, 256, 0, stream>>>(u, posx, post, We1, be1, We2, be2, h, h_bf);

    {
        int tot1 = 6 * 9 * 512;
        int tot2 = 6 * 4 * 512;
        pack_kernel<<<(tot1 + 255) / 256, 256, 0, stream>>>(Wm1, Wm1p, 283, 9, tot1);
        pack_kernel<<<(tot2 + 255) / 256, 256, 0, stream>>>(Wm2, Wm2p, 128, 4, tot2);
        pack_kernel<<<(tot1 + 255) / 256, 256, 0, stream>>>(Wu1, Wu1p, 257, 9, tot1);
        pack_kernel<<<(tot2 + 255) / 256, 256, 0, stream>>>(Wu2, Wu2p, 128, 4, tot2);
    }

    for (int l = 0; l < 6; ++l) {
        hipMemsetAsync(agg, 0, (size_t)N_NODES * 128 * sizeof(float), stream);
        hipMemsetAsync(stats, 0, 2 * NB * 128 * sizeof(float), stream);
        message_kernel<<<N_EDGES / 64, 256, 0, stream>>>(
            h_bf, u, posx, post, srcp, tgtp, perm,
            Wm1p + (size_t)l * 9 * 4096, bm1 + l * 128,
            Wm2p + (size_t)l * 4 * 4096, bm2 + l * 128, agg);
        update_kernel<<<N_NODES / 64, 256, 0, stream>>>(
            h, h_bf, agg, deg, post,
            Wu1p + (size_t)l * 9 * 4096, bu1 + l * 128,
            Wu2p + (size_t)l * 4 * 4096, bu2 + l * 128, stats);
        norm_kernel<<<(N_NODES * 128) / 256, 256, 0, stream>>>(h, h_bf, stats);
    }

    conv_kernel<<<N_NODES, 64, 0, stream>>>(h, u, Wc1, bc1, Wc2, bc2, out);
}